// Round 1
// baseline (1138.134 us; speedup 1.0000x reference)
//
#include <hip/hip_runtime.h>

#define NB 16
#define NN 2048
#define NP 512
#define NS 32
#define NC 64

// d2 with explicit rounding (no FMA contraction) to bit-match the reference's
// elementwise square + 3-term reduce: ((dx*dx + dy*dy) + dz*dz)
__device__ __forceinline__ float sqdist(float dx, float dy, float dz) {
  return __fadd_rn(__fadd_rn(__fmul_rn(dx, dx), __fmul_rn(dy, dy)), __fmul_rn(dz, dz));
}

__device__ __forceinline__ unsigned long long umax64(unsigned long long a, unsigned long long b) {
  return a > b ? a : b;
}

__device__ __forceinline__ unsigned long long shflx64(unsigned long long v, int m) {
  unsigned lo = (unsigned)(v & 0xffffffffull);
  unsigned hi = (unsigned)(v >> 32);
  lo = __shfl_xor(lo, m, 64);
  hi = __shfl_xor(hi, m, 64);
  return ((unsigned long long)hi << 32) | lo;
}

// ---------------------------------------------------------------------------
// prep: features (B,C,N) -> featT (B,N,C); xyz (B,3,N) -> xyzT (B,N,4) float4
// ---------------------------------------------------------------------------
__global__ __launch_bounds__(256) void prep_kernel(const float* __restrict__ feat,
                                                   const float* __restrict__ xyz,
                                                   float* __restrict__ featT,
                                                   float* __restrict__ xyzT) {
  __shared__ float tile[64][65];
  const int b = blockIdx.x;
  const int n0 = blockIdx.y * 64;
  const int t = threadIdx.x;
  const int g = t >> 6, l = t & 63;
  if (g == 0) {
    int n = n0 + l;
    float4 q;
    q.x = xyz[(size_t)b * 3 * NN + n];
    q.y = xyz[(size_t)b * 3 * NN + NN + n];
    q.z = xyz[(size_t)b * 3 * NN + 2 * NN + n];
    q.w = 0.f;
    ((float4*)xyzT)[(size_t)b * NN + n] = q;
  }
#pragma unroll
  for (int r = 0; r < 16; ++r) {
    int c = g * 16 + r;
    tile[c][l] = feat[((size_t)b * NC + c) * NN + n0 + l];
  }
  __syncthreads();
#pragma unroll
  for (int r = 0; r < 16; ++r) {
    int nl = g * 16 + r;
    featT[((size_t)(b * NN + n0 + nl)) * NC + l] = tile[l][nl];
  }
}

// ---------------------------------------------------------------------------
// FPS: one block per batch, 512 threads, 4 points/thread, dist in registers.
// Exact argmax-first-occurrence via u64 key = (dist_bits<<32) | (N-1-n).
// Writes new_xyz (B,3,512) directly into d_out.
// ---------------------------------------------------------------------------
__global__ __launch_bounds__(512) void fps_kernel(const float* __restrict__ xyz,
                                                  float* __restrict__ newxyz) {
  const int b = blockIdx.x;
  const int t = threadIdx.x;
  const float* X = xyz + (size_t)b * 3 * NN;
  float px[4], py[4], pz[4], dist[4];
#pragma unroll
  for (int j = 0; j < 4; ++j) {
    int n = t + 512 * j;
    px[j] = X[n];
    py[j] = X[NN + n];
    pz[j] = X[2 * NN + n];
    dist[j] = 1e10f;
  }
  __shared__ unsigned long long part[2][8];
  int far = 0;
  for (int i = 0; i < NP; ++i) {
    const int fs = __builtin_amdgcn_readfirstlane(far);
    const float cx = X[fs], cy = X[NN + fs], cz = X[2 * NN + fs];
    if (t == 0) {
      newxyz[b * 3 * NP + i] = cx;
      newxyz[b * 3 * NP + NP + i] = cy;
      newxyz[b * 3 * NP + 2 * NP + i] = cz;
    }
    unsigned long long best = 0;
#pragma unroll
    for (int j = 0; j < 4; ++j) {
      float d2 = sqdist(px[j] - cx, py[j] - cy, pz[j] - cz);
      dist[j] = fminf(dist[j], d2);
      unsigned long long key =
          ((unsigned long long)__float_as_uint(dist[j]) << 32) | (unsigned)(NN - 1 - (t + 512 * j));
      best = umax64(best, key);
    }
#pragma unroll
    for (int m = 1; m < 64; m <<= 1) best = umax64(best, shflx64(best, m));
    const int buf = i & 1;
    if ((t & 63) == 0) part[buf][t >> 6] = best;
    __syncthreads();
    unsigned long long r0 = umax64(part[buf][0], part[buf][1]);
    unsigned long long r1 = umax64(part[buf][2], part[buf][3]);
    unsigned long long r2 = umax64(part[buf][4], part[buf][5]);
    unsigned long long r3 = umax64(part[buf][6], part[buf][7]);
    r0 = umax64(r0, r1);
    r2 = umax64(r2, r3);
    r0 = umax64(r0, r2);
    far = (NN - 1) - (int)(r0 & 0xffffffffull);
  }
}

// ---------------------------------------------------------------------------
// Ball query: one wave per sampled point; ordered first-32 hit selection via
// ballot + prefix popcount; pad with first hit. Exact d2 < (float)(0.2*0.2).
// ---------------------------------------------------------------------------
__global__ __launch_bounds__(256) void ball_kernel(const float* __restrict__ xyz,
                                                   const float* __restrict__ newxyz,
                                                   int* __restrict__ idx) {
  const int b = blockIdx.x;
  const int s = blockIdx.y * 4 + (threadIdx.x >> 6);
  const int lane = threadIdx.x & 63;
  const float* X = xyz + (size_t)b * 3 * NN;
  const float cx = newxyz[b * 3 * NP + s];
  const float cy = newxyz[b * 3 * NP + NP + s];
  const float cz = newxyz[b * 3 * NP + 2 * NP + s];
  int* row = idx + ((size_t)(b * NP + s)) * NS;
  const float r2 = (float)(0.2 * 0.2);
  int total = 0, first = 0;
  bool havefirst = false;
  for (int c0 = 0; c0 < NN; c0 += 64) {
    int n = c0 + lane;
    float d2 = sqdist(X[n] - cx, X[NN + n] - cy, X[2 * NN + n] - cz);
    bool hit = d2 < r2;
    unsigned long long mask = __ballot(hit);
    if (!havefirst && mask) {
      first = c0 + __builtin_ctzll(mask);
      havefirst = true;
    }
    if (hit) {
      int pos = total + (int)__popcll(mask & ((1ull << lane) - 1ull));
      if (pos < NS) row[pos] = n;
    }
    total += (int)__popcll(mask);
    if (total >= NS) break;
  }
  if (total < NS && lane >= total && lane < NS) row[lane] = first;
}

// ---------------------------------------------------------------------------
// Gather + 3-layer MLP + max-pool. One thread per (s,k) column; weights staged
// in LDS (W1 padded to stride 68; W3 in two 64KB halves), activations in regs,
// k-maxpool via shuffle over the 32-lane half-wave.
// ---------------------------------------------------------------------------
__global__ __launch_bounds__(256, 2) void mlp_kernel(
    const float* __restrict__ xyzT, const float* __restrict__ featT, const int* __restrict__ idx,
    const float* __restrict__ newxyz, const float* __restrict__ W1, const float* __restrict__ b1,
    const float* __restrict__ W2, const float* __restrict__ b2, const float* __restrict__ W3,
    const float* __restrict__ b3, float* __restrict__ out) {
  __shared__ float wlds[16384];  // 64 KB
  const int b = blockIdx.x;
  const int t = threadIdx.x;
  const int sl = t >> 5, k = t & 31;
  const int s = blockIdx.y * 8 + sl;

  // stage W1 (64x67 -> stride-68 padded) and W2 (128x64)
  for (int i = t; i < 64 * 68; i += 256) {
    int r = i / 68, c = i - r * 68;
    wlds[i] = (c < 67) ? W1[r * 67 + c] : 0.f;
  }
  for (int i = t; i < 128 * 64; i += 256) wlds[4352 + i] = W2[i];

  // gather column h (3 rel-xyz + 64 features)
  const int n = idx[((size_t)(b * NP + s)) * NS + k];
  float h[68];
  {
    float4 p = ((const float4*)xyzT)[(size_t)b * NN + n];
    float cx = newxyz[b * 3 * NP + s];
    float cy = newxyz[b * 3 * NP + NP + s];
    float cz = newxyz[b * 3 * NP + 2 * NP + s];
    h[0] = p.x - cx;
    h[1] = p.y - cy;
    h[2] = p.z - cz;
    const float4* F = (const float4*)(featT + ((size_t)(b * NN + n)) * NC);
#pragma unroll
    for (int i = 0; i < 16; ++i) {
      float4 f = F[i];
      h[3 + 4 * i] = f.x;
      h[4 + 4 * i] = f.y;
      h[5 + 4 * i] = f.z;
      h[6 + 4 * i] = f.w;
    }
    h[67] = 0.f;
  }
  __syncthreads();

  // layer 1: 67 -> 64
  float a1[64];
#pragma unroll 2
  for (int o = 0; o < 64; ++o) {
    float acc = b1[o];
    const float* w = wlds + o * 68;
#pragma unroll
    for (int c = 0; c < 68; c += 4) {
      float4 wv = *(const float4*)(w + c);
      acc = fmaf(wv.x, h[c], acc);
      acc = fmaf(wv.y, h[c + 1], acc);
      acc = fmaf(wv.z, h[c + 2], acc);
      acc = fmaf(wv.w, h[c + 3], acc);
    }
    a1[o] = fmaxf(acc, 0.f);
  }

  // layer 2: 64 -> 128
  float a2[128];
#pragma unroll 2
  for (int o = 0; o < 128; ++o) {
    float acc = b2[o];
    const float* w = wlds + 4352 + o * 64;
#pragma unroll
    for (int c = 0; c < 64; c += 4) {
      float4 wv = *(const float4*)(w + c);
      acc = fmaf(wv.x, a1[c], acc);
      acc = fmaf(wv.y, a1[c + 1], acc);
      acc = fmaf(wv.z, a1[c + 2], acc);
      acc = fmaf(wv.w, a1[c + 3], acc);
    }
    a2[o] = fmaxf(acc, 0.f);
  }

  // layer 3: 128 -> 256 in two LDS halves, fused k-maxpool
  float* out2 = out + NB * 3 * NP;
#pragma unroll 1
  for (int half = 0; half < 2; ++half) {
    __syncthreads();
    const float* W3h = W3 + half * 128 * 128;
    for (int i = t; i < 128 * 128; i += 256) wlds[i] = W3h[i];
    __syncthreads();
#pragma unroll 2
    for (int oo = 0; oo < 128; ++oo) {
      float acc = b3[half * 128 + oo];
      const float* w = wlds + oo * 128;
#pragma unroll
      for (int c = 0; c < 128; c += 4) {
        float4 wv = *(const float4*)(w + c);
        acc = fmaf(wv.x, a2[c], acc);
        acc = fmaf(wv.y, a2[c + 1], acc);
        acc = fmaf(wv.z, a2[c + 2], acc);
        acc = fmaf(wv.w, a2[c + 3], acc);
      }
      float v = fmaxf(acc, 0.f);
#pragma unroll
      for (int m = 16; m >= 1; m >>= 1) v = fmaxf(v, __shfl_xor(v, m, 64));
      if (k == 0) out2[((size_t)(b * 256) + half * 128 + oo) * NP + s] = v;
    }
  }
}

extern "C" void kernel_launch(void* const* d_in, const int* in_sizes, int n_in, void* d_out,
                              int out_size, void* d_ws, size_t ws_size, hipStream_t stream) {
  const float* xyz = (const float*)d_in[0];
  const float* feat = (const float*)d_in[1];
  const float* W1 = (const float*)d_in[2];
  const float* b1 = (const float*)d_in[3];
  const float* W2 = (const float*)d_in[4];
  const float* b2 = (const float*)d_in[5];
  const float* W3 = (const float*)d_in[6];
  const float* b3 = (const float*)d_in[7];
  float* out = (float*)d_out;
  char* ws = (char*)d_ws;
  float* xyzT = (float*)ws;                        // 16*2048 float4 = 512 KB
  float* featT = (float*)(ws + 524288);            // 16*2048*64 f32 = 8 MB
  int* idx = (int*)(ws + 524288 + 8388608);        // 16*512*32 int = 1 MB

  hipLaunchKernelGGL(prep_kernel, dim3(NB, 32), dim3(256), 0, stream, feat, xyz, featT, xyzT);
  hipLaunchKernelGGL(fps_kernel, dim3(NB), dim3(512), 0, stream, xyz, out);
  hipLaunchKernelGGL(ball_kernel, dim3(NB, 128), dim3(256), 0, stream, xyz, out, idx);
  hipLaunchKernelGGL(mlp_kernel, dim3(NB, 64), dim3(256), 0, stream, xyzT, featT, idx, out, W1, b1,
                     W2, b2, W3, b3, out);
}

// Round 2
// 710.289 us; speedup vs baseline: 1.6024x; 1.6024x over previous
//
#include <hip/hip_runtime.h>

#define NB 16
#define NN 2048
#define NP 512
#define NS 32
#define NC 64

// d2 with explicit rounding (no FMA contraction) to bit-match the reference's
// elementwise square + 3-term reduce: ((dx*dx + dy*dy) + dz*dz)
__device__ __forceinline__ float sqdist(float dx, float dy, float dz) {
  return __fadd_rn(__fadd_rn(__fmul_rn(dx, dx), __fmul_rn(dy, dy)), __fmul_rn(dz, dz));
}

__device__ __forceinline__ unsigned long long umax64(unsigned long long a, unsigned long long b) {
  return a > b ? a : b;
}

__device__ __forceinline__ unsigned long long shflx64(unsigned long long v, int m) {
  unsigned lo = (unsigned)(v & 0xffffffffull);
  unsigned hi = (unsigned)(v >> 32);
  lo = __shfl_xor(lo, m, 64);
  hi = __shfl_xor(hi, m, 64);
  return ((unsigned long long)hi << 32) | lo;
}

// ---------------------------------------------------------------------------
// prep: features (B,C,N) -> featT (B,N,C); xyz (B,3,N) -> xyzT (B,N,4) float4;
// block (0,0) additionally packs W1 (64x67) -> W1p (64x68, col 67 zeroed).
// ---------------------------------------------------------------------------
__global__ __launch_bounds__(256) void prep_kernel(const float* __restrict__ feat,
                                                   const float* __restrict__ xyz,
                                                   const float* __restrict__ W1,
                                                   float* __restrict__ featT,
                                                   float* __restrict__ xyzT,
                                                   float* __restrict__ W1p) {
  __shared__ float tile[64][65];
  const int b = blockIdx.x;
  const int n0 = blockIdx.y * 64;
  const int t = threadIdx.x;
  const int g = t >> 6, l = t & 63;
  if (b == 0 && blockIdx.y == 0) {
    for (int i = t; i < 64 * 68; i += 256) {
      int r = i / 68, c = i - r * 68;
      W1p[i] = (c < 67) ? W1[r * 67 + c] : 0.f;
    }
  }
  if (g == 0) {
    int n = n0 + l;
    float4 q;
    q.x = xyz[(size_t)b * 3 * NN + n];
    q.y = xyz[(size_t)b * 3 * NN + NN + n];
    q.z = xyz[(size_t)b * 3 * NN + 2 * NN + n];
    q.w = 0.f;
    ((float4*)xyzT)[(size_t)b * NN + n] = q;
  }
#pragma unroll
  for (int r = 0; r < 16; ++r) {
    int c = g * 16 + r;
    tile[c][l] = feat[((size_t)b * NC + c) * NN + n0 + l];
  }
  __syncthreads();
#pragma unroll
  for (int r = 0; r < 16; ++r) {
    int nl = g * 16 + r;
    featT[((size_t)(b * NN + n0 + nl)) * NC + l] = tile[l][nl];
  }
}

// ---------------------------------------------------------------------------
// FPS (unchanged, bit-exact): one block per batch, u64-key argmax.
// ---------------------------------------------------------------------------
__global__ __launch_bounds__(512) void fps_kernel(const float* __restrict__ xyz,
                                                  float* __restrict__ newxyz) {
  const int b = blockIdx.x;
  const int t = threadIdx.x;
  const float* X = xyz + (size_t)b * 3 * NN;
  float px[4], py[4], pz[4], dist[4];
#pragma unroll
  for (int j = 0; j < 4; ++j) {
    int n = t + 512 * j;
    px[j] = X[n];
    py[j] = X[NN + n];
    pz[j] = X[2 * NN + n];
    dist[j] = 1e10f;
  }
  __shared__ unsigned long long part[2][8];
  int far = 0;
  for (int i = 0; i < NP; ++i) {
    const int fs = __builtin_amdgcn_readfirstlane(far);
    const float cx = X[fs], cy = X[NN + fs], cz = X[2 * NN + fs];
    if (t == 0) {
      newxyz[b * 3 * NP + i] = cx;
      newxyz[b * 3 * NP + NP + i] = cy;
      newxyz[b * 3 * NP + 2 * NP + i] = cz;
    }
    unsigned long long best = 0;
#pragma unroll
    for (int j = 0; j < 4; ++j) {
      float d2 = sqdist(px[j] - cx, py[j] - cy, pz[j] - cz);
      dist[j] = fminf(dist[j], d2);
      unsigned long long key =
          ((unsigned long long)__float_as_uint(dist[j]) << 32) | (unsigned)(NN - 1 - (t + 512 * j));
      best = umax64(best, key);
    }
#pragma unroll
    for (int m = 1; m < 64; m <<= 1) best = umax64(best, shflx64(best, m));
    const int buf = i & 1;
    if ((t & 63) == 0) part[buf][t >> 6] = best;
    __syncthreads();
    unsigned long long r0 = umax64(part[buf][0], part[buf][1]);
    unsigned long long r1 = umax64(part[buf][2], part[buf][3]);
    unsigned long long r2 = umax64(part[buf][4], part[buf][5]);
    unsigned long long r3 = umax64(part[buf][6], part[buf][7]);
    r0 = umax64(r0, r1);
    r2 = umax64(r2, r3);
    r0 = umax64(r0, r2);
    far = (NN - 1) - (int)(r0 & 0xffffffffull);
  }
}

// ---------------------------------------------------------------------------
// Ball query (unchanged, bit-exact).
// ---------------------------------------------------------------------------
__global__ __launch_bounds__(256) void ball_kernel(const float* __restrict__ xyz,
                                                   const float* __restrict__ newxyz,
                                                   int* __restrict__ idx) {
  const int b = blockIdx.x;
  const int s = blockIdx.y * 4 + (threadIdx.x >> 6);
  const int lane = threadIdx.x & 63;
  const float* X = xyz + (size_t)b * 3 * NN;
  const float cx = newxyz[b * 3 * NP + s];
  const float cy = newxyz[b * 3 * NP + NP + s];
  const float cz = newxyz[b * 3 * NP + 2 * NP + s];
  int* row = idx + ((size_t)(b * NP + s)) * NS;
  const float r2 = (float)(0.2 * 0.2);
  int total = 0, first = 0;
  bool havefirst = false;
  for (int c0 = 0; c0 < NN; c0 += 64) {
    int n = c0 + lane;
    float d2 = sqdist(X[n] - cx, X[NN + n] - cy, X[2 * NN + n] - cz);
    bool hit = d2 < r2;
    unsigned long long mask = __ballot(hit);
    if (!havefirst && mask) {
      first = c0 + __builtin_ctzll(mask);
      havefirst = true;
    }
    if (hit) {
      int pos = total + (int)__popcll(mask & ((1ull << lane) - 1ull));
      if (pos < NS) row[pos] = n;
    }
    total += (int)__popcll(mask);
    if (total >= NS) break;
  }
  if (total < NS && lane >= total && lane < NS) row[lane] = first;
}

// ---------------------------------------------------------------------------
// Fused gather + 3-layer MLP + max-pool, GEMM-structured:
//  - activations in LDS (h 68x64 -> a1 64x64 -> a2 128x64; a2 aliases h)
//  - weights streamed from global (L2-resident broadcast reads)
//  - per-thread register tiles with ALL indices compile-time (no scratch)
//  - fused k-maxpool via shuffle; block covers 2 s-values (64 columns)
// ---------------------------------------------------------------------------
__global__ __launch_bounds__(256, 3) void mlp_kernel(
    const float* __restrict__ xyzT, const float* __restrict__ featT, const int* __restrict__ idx,
    const float* __restrict__ newxyz, const float* __restrict__ W1p, const float* __restrict__ b1,
    const float* __restrict__ W2, const float* __restrict__ b2, const float* __restrict__ W3,
    const float* __restrict__ b3, float* __restrict__ out) {
  __shared__ float reg1[128 * 64];  // h (rows 0..67) then a2 (rows 0..127); 32 KB
  __shared__ float a1s[64 * 64];    // 16 KB
  const int b = blockIdx.x;
  const int s0 = blockIdx.y * 2;
  const int t = threadIdx.x;

  // ---- gather: h[68][64] ----
  {
    const int c = t & 63;        // column
    const int q = t >> 6;        // feature quarter 0..3
    const int s = s0 + (c >> 5);
    const int k = c & 31;
    const int n = idx[((size_t)(b * NP + s)) * NS + k];
    const float4* F = (const float4*)(featT + ((size_t)(b * NN + n)) * NC);
#pragma unroll
    for (int j = 0; j < 4; ++j) {
      float4 f = F[q * 4 + j];
      reg1[(3 + q * 16 + 4 * j + 0) * 64 + c] = f.x;
      reg1[(3 + q * 16 + 4 * j + 1) * 64 + c] = f.y;
      reg1[(3 + q * 16 + 4 * j + 2) * 64 + c] = f.z;
      reg1[(3 + q * 16 + 4 * j + 3) * 64 + c] = f.w;
    }
    if (q == 0) {
      float4 p = ((const float4*)xyzT)[(size_t)b * NN + n];
      float cx = newxyz[b * 3 * NP + s];
      float cy = newxyz[b * 3 * NP + NP + s];
      float cz = newxyz[b * 3 * NP + 2 * NP + s];
      reg1[0 * 64 + c] = p.x - cx;
      reg1[1 * 64 + c] = p.y - cy;
      reg1[2 * 64 + c] = p.z - cz;
      reg1[67 * 64 + c] = 0.f;
    }
  }
  __syncthreads();

  const int tx = t & 15;   // column group: cols tx*4..tx*4+3
  const int ty = t >> 4;   // row group

  // ---- layer 1: 68 -> 64, rows ty*4..+3 ----
  {
    float acc[4][4];
#pragma unroll
    for (int i = 0; i < 4; ++i) {
      float bi = b1[ty * 4 + i];
#pragma unroll
      for (int j = 0; j < 4; ++j) acc[i][j] = bi;
    }
    for (int kk = 0; kk < 68; kk += 4) {
      float wr[4][4], hr[4][4];
#pragma unroll
      for (int i = 0; i < 4; ++i) {
        float4 v = *(const float4*)(W1p + (ty * 4 + i) * 68 + kk);
        wr[i][0] = v.x; wr[i][1] = v.y; wr[i][2] = v.z; wr[i][3] = v.w;
      }
#pragma unroll
      for (int jj = 0; jj < 4; ++jj) {
        float4 v = *(const float4*)(&reg1[(kk + jj) * 64 + tx * 4]);
        hr[jj][0] = v.x; hr[jj][1] = v.y; hr[jj][2] = v.z; hr[jj][3] = v.w;
      }
#pragma unroll
      for (int i = 0; i < 4; ++i)
#pragma unroll
        for (int j = 0; j < 4; ++j)
#pragma unroll
          for (int jj = 0; jj < 4; ++jj) acc[i][j] = fmaf(wr[i][jj], hr[jj][j], acc[i][j]);
    }
    __syncthreads();  // h fully consumed before a1 store? a1s separate; this sync
                      // orders h-reads before reg1 is overwritten by a2 later.
#pragma unroll
    for (int i = 0; i < 4; ++i) {
      float4 v;
      v.x = fmaxf(acc[i][0], 0.f);
      v.y = fmaxf(acc[i][1], 0.f);
      v.z = fmaxf(acc[i][2], 0.f);
      v.w = fmaxf(acc[i][3], 0.f);
      *(float4*)(&a1s[(ty * 4 + i) * 64 + tx * 4]) = v;
    }
  }
  __syncthreads();

  // ---- layer 2: 64 -> 128, rows ty*8..+7, a2 overwrites reg1 ----
  {
    float acc[8][4];
#pragma unroll
    for (int i = 0; i < 8; ++i) {
      float bi = b2[ty * 8 + i];
#pragma unroll
      for (int j = 0; j < 4; ++j) acc[i][j] = bi;
    }
#pragma unroll 2
    for (int kk = 0; kk < 64; kk += 4) {
      float wr[8][4], hr[4][4];
#pragma unroll
      for (int i = 0; i < 8; ++i) {
        float4 v = *(const float4*)(W2 + (ty * 8 + i) * 64 + kk);
        wr[i][0] = v.x; wr[i][1] = v.y; wr[i][2] = v.z; wr[i][3] = v.w;
      }
#pragma unroll
      for (int jj = 0; jj < 4; ++jj) {
        float4 v = *(const float4*)(&a1s[(kk + jj) * 64 + tx * 4]);
        hr[jj][0] = v.x; hr[jj][1] = v.y; hr[jj][2] = v.z; hr[jj][3] = v.w;
      }
#pragma unroll
      for (int i = 0; i < 8; ++i)
#pragma unroll
        for (int j = 0; j < 4; ++j)
#pragma unroll
          for (int jj = 0; jj < 4; ++jj) acc[i][j] = fmaf(wr[i][jj], hr[jj][j], acc[i][j]);
    }
#pragma unroll
    for (int i = 0; i < 8; ++i) {
      float4 v;
      v.x = fmaxf(acc[i][0], 0.f);
      v.y = fmaxf(acc[i][1], 0.f);
      v.z = fmaxf(acc[i][2], 0.f);
      v.w = fmaxf(acc[i][3], 0.f);
      *(float4*)(&reg1[(ty * 8 + i) * 64 + tx * 4]) = v;
    }
  }
  __syncthreads();

  // ---- layer 3: 128 -> 256 in 4 row-chunks of 64, fused maxpool ----
  float* out2 = out + NB * 3 * NP;
#pragma unroll 1
  for (int ch = 0; ch < 4; ++ch) {
    float acc[4][4];
#pragma unroll
    for (int i = 0; i < 4; ++i) {
      float bi = b3[ch * 64 + ty * 4 + i];
#pragma unroll
      for (int j = 0; j < 4; ++j) acc[i][j] = bi;
    }
#pragma unroll 2
    for (int kk = 0; kk < 128; kk += 4) {
      float wr[4][4], hr[4][4];
#pragma unroll
      for (int i = 0; i < 4; ++i) {
        float4 v = *(const float4*)(W3 + ((size_t)(ch * 64 + ty * 4 + i)) * 128 + kk);
        wr[i][0] = v.x; wr[i][1] = v.y; wr[i][2] = v.z; wr[i][3] = v.w;
      }
#pragma unroll
      for (int jj = 0; jj < 4; ++jj) {
        float4 v = *(const float4*)(&reg1[(kk + jj) * 64 + tx * 4]);
        hr[jj][0] = v.x; hr[jj][1] = v.y; hr[jj][2] = v.z; hr[jj][3] = v.w;
      }
#pragma unroll
      for (int i = 0; i < 4; ++i)
#pragma unroll
        for (int j = 0; j < 4; ++j)
#pragma unroll
          for (int jj = 0; jj < 4; ++jj) acc[i][j] = fmaf(wr[i][jj], hr[jj][j], acc[i][j]);
    }
#pragma unroll
    for (int i = 0; i < 4; ++i) {
      float pm = fmaxf(fmaxf(fmaxf(acc[i][0], acc[i][1]), fmaxf(acc[i][2], acc[i][3])), 0.f);
      pm = fmaxf(pm, __shfl_xor(pm, 1, 64));
      pm = fmaxf(pm, __shfl_xor(pm, 2, 64));
      pm = fmaxf(pm, __shfl_xor(pm, 4, 64));
      if ((tx & 7) == 0)
        out2[((size_t)(b * 256 + ch * 64 + ty * 4 + i)) * NP + s0 + (tx >> 3)] = pm;
    }
  }
}

extern "C" void kernel_launch(void* const* d_in, const int* in_sizes, int n_in, void* d_out,
                              int out_size, void* d_ws, size_t ws_size, hipStream_t stream) {
  const float* xyz = (const float*)d_in[0];
  const float* feat = (const float*)d_in[1];
  const float* W1 = (const float*)d_in[2];
  const float* b1 = (const float*)d_in[3];
  const float* W2 = (const float*)d_in[4];
  const float* b2 = (const float*)d_in[5];
  const float* W3 = (const float*)d_in[6];
  const float* b3 = (const float*)d_in[7];
  float* out = (float*)d_out;
  char* ws = (char*)d_ws;
  float* xyzT = (float*)ws;                              // 16*2048 float4 = 512 KB
  float* featT = (float*)(ws + 524288);                  // 16*2048*64 f32 = 8 MB
  int* idx = (int*)(ws + 524288 + 8388608);              // 16*512*32 int = 1 MB
  float* W1p = (float*)(ws + 524288 + 8388608 + 1048576);  // 64*68 f32 ≈ 17.4 KB

  hipLaunchKernelGGL(prep_kernel, dim3(NB, 32), dim3(256), 0, stream, feat, xyz, W1, featT, xyzT,
                     W1p);
  hipLaunchKernelGGL(fps_kernel, dim3(NB), dim3(512), 0, stream, xyz, out);
  hipLaunchKernelGGL(ball_kernel, dim3(NB, 128), dim3(256), 0, stream, xyz, out, idx);
  hipLaunchKernelGGL(mlp_kernel, dim3(NB, NP / 2), dim3(256), 0, stream, xyzT, featT, idx, out,
                     W1p, b1, W2, b2, W3, b3, out);
}

// Round 3
// 465.014 us; speedup vs baseline: 2.4475x; 1.5275x over previous
//
#include <hip/hip_runtime.h>

#define NB 16
#define NN 2048
#define NP 512
#define NS 32
#define NC 64

typedef _Float16 f16x8 __attribute__((ext_vector_type(8)));
typedef _Float16 f16x4 __attribute__((ext_vector_type(4)));
typedef float f32x4 __attribute__((ext_vector_type(4)));

// d2 with explicit rounding (no FMA contraction) to bit-match the reference
__device__ __forceinline__ float sqdist(float dx, float dy, float dz) {
  return __fadd_rn(__fadd_rn(__fmul_rn(dx, dx), __fmul_rn(dy, dy)), __fmul_rn(dz, dz));
}

template <int CTRL>
__device__ __forceinline__ unsigned long long dppmax(unsigned long long k) {
  unsigned lo = (unsigned)k, hi = (unsigned)(k >> 32);
  unsigned lo2 = (unsigned)__builtin_amdgcn_update_dpp(0, (int)lo, CTRL, 0xf, 0xf, true);
  unsigned hi2 = (unsigned)__builtin_amdgcn_update_dpp(0, (int)hi, CTRL, 0xf, 0xf, true);
  unsigned long long k2 = ((unsigned long long)hi2 << 32) | lo2;
  return k > k2 ? k : k2;
}

// ---------------------------------------------------------------------------
// prep: features (B,C,N) f32 -> featF (B,N,C) f16; xyz -> xyzT (B,N,4) f32
// ---------------------------------------------------------------------------
__global__ __launch_bounds__(256) void prep_kernel(const float* __restrict__ feat,
                                                   const float* __restrict__ xyz,
                                                   _Float16* __restrict__ featF,
                                                   float* __restrict__ xyzT) {
  __shared__ float tile[64][65];
  const int b = blockIdx.x;
  const int n0 = blockIdx.y * 64;
  const int t = threadIdx.x;
  const int g = t >> 6, l = t & 63;
  if (g == 0) {
    int n = n0 + l;
    float4 q;
    q.x = xyz[(size_t)b * 3 * NN + n];
    q.y = xyz[(size_t)b * 3 * NN + NN + n];
    q.z = xyz[(size_t)b * 3 * NN + 2 * NN + n];
    q.w = 0.f;
    ((float4*)xyzT)[(size_t)b * NN + n] = q;
  }
#pragma unroll
  for (int r = 0; r < 16; ++r) {
    int c = g * 16 + r;
    tile[c][l] = feat[((size_t)b * NC + c) * NN + n0 + l];
  }
  __syncthreads();
#pragma unroll
  for (int r = 0; r < 16; ++r) {
    int nl = g * 16 + r;
    featF[((size_t)(b * NN + n0 + nl)) * NC + l] = (_Float16)tile[l][nl];
  }
}

// ---------------------------------------------------------------------------
// weight conversion to f16. W1f is 64x96: cols 0..63 = feature cols (orig 3..66),
// cols 64..66 = xyz cols (orig 0..2), 67..95 = zero. (K-permutation applied
// identically to the h layout -> exact same dot products.)
// ---------------------------------------------------------------------------
__global__ __launch_bounds__(256) void wconv_kernel(const float* __restrict__ W1,
                                                    const float* __restrict__ W2,
                                                    const float* __restrict__ W3,
                                                    _Float16* __restrict__ W1f,
                                                    _Float16* __restrict__ W2f,
                                                    _Float16* __restrict__ W3f) {
  int i = blockIdx.x * 256 + threadIdx.x;
  if (i < 64 * 96) {
    int o = i / 96, k = i - o * 96;
    float v = (k < 64) ? W1[o * 67 + 3 + k] : ((k < 67) ? W1[o * 67 + (k - 64)] : 0.f);
    W1f[i] = (_Float16)v;
  }
  if (i < 128 * 64) W2f[i] = (_Float16)W2[i];
  if (i < 256 * 128) W3f[i] = (_Float16)W3[i];
}

// ---------------------------------------------------------------------------
// FPS v2: 256 threads, 8 pts/thread. Exact u64 key = (dist_bits<<32)|(N-1-n).
// DPP wave reduce (shr1/2/4/8 + bcast15/31), candidates carry xyz so the
// next centroid needs no re-fetch. One barrier/iter, parity double-buffer.
// ---------------------------------------------------------------------------
__global__ __launch_bounds__(256) void fps_kernel(const float* __restrict__ xyz,
                                                  float* __restrict__ newxyz) {
  const int b = blockIdx.x, t = threadIdx.x;
  const int w = t >> 6;
  const float* X = xyz + (size_t)b * 3 * NN;
  float px[8], py[8], pz[8], dist[8];
  unsigned lo[8];
#pragma unroll
  for (int j = 0; j < 8; ++j) {
    int n = t + 256 * j;
    px[j] = X[n];
    py[j] = X[NN + n];
    pz[j] = X[2 * NN + n];
    dist[j] = 1e10f;
    lo[j] = (unsigned)(NN - 1 - n);
  }
  __shared__ unsigned cnd[2][4][8];
  float cx = X[0], cy = X[NN], cz = X[2 * NN];
  for (int i = 0; i < NP; ++i) {
    if (t == 0) {
      newxyz[b * 3 * NP + i] = cx;
      newxyz[b * 3 * NP + NP + i] = cy;
      newxyz[b * 3 * NP + 2 * NP + i] = cz;
    }
    unsigned long long loc = 0;
    int bj = 0;
#pragma unroll
    for (int j = 0; j < 8; ++j) {
      float d2 = sqdist(px[j] - cx, py[j] - cy, pz[j] - cz);
      dist[j] = fminf(dist[j], d2);
      unsigned long long key = ((unsigned long long)__float_as_uint(dist[j]) << 32) | lo[j];
      if (key > loc) {
        loc = key;
        bj = j;
      }
    }
    // owner xyz select (issues in parallel with the dpp dependency chain)
    float bx = px[0], by = py[0], bz = pz[0];
#pragma unroll
    for (int j = 1; j < 8; ++j)
      if (bj == j) { bx = px[j]; by = py[j]; bz = pz[j]; }
    unsigned long long red = loc;
    red = dppmax<0x111>(red);  // row_shr:1
    red = dppmax<0x112>(red);  // row_shr:2
    red = dppmax<0x114>(red);  // row_shr:4
    red = dppmax<0x118>(red);  // row_shr:8
    red = dppmax<0x142>(red);  // row_bcast:15
    red = dppmax<0x143>(red);  // row_bcast:31  -> lane 63 has wave max
    unsigned wlo = (unsigned)__builtin_amdgcn_readlane((int)(unsigned)(red & 0xffffffffull), 63);
    unsigned whi = (unsigned)__builtin_amdgcn_readlane((int)(unsigned)(red >> 32), 63);
    unsigned long long wkey = ((unsigned long long)whi << 32) | wlo;
    const int buf = i & 1;
    if (loc == wkey) {  // exactly one lane per wave (keys unique)
      unsigned* c = cnd[buf][w];
      c[0] = wlo;
      c[1] = whi;
      c[2] = __float_as_uint(bx);
      c[3] = __float_as_uint(by);
      c[4] = __float_as_uint(bz);
    }
    __syncthreads();
    uint4 q0 = *(const uint4*)cnd[buf][0];
    unsigned z0 = cnd[buf][0][4];
    uint4 q1 = *(const uint4*)cnd[buf][1];
    unsigned z1 = cnd[buf][1][4];
    uint4 q2 = *(const uint4*)cnd[buf][2];
    unsigned z2 = cnd[buf][2][4];
    uint4 q3 = *(const uint4*)cnd[buf][3];
    unsigned z3 = cnd[buf][3][4];
    unsigned long long k0 = ((unsigned long long)q0.y << 32) | q0.x;
    unsigned long long k1 = ((unsigned long long)q1.y << 32) | q1.x;
    unsigned long long k2 = ((unsigned long long)q2.y << 32) | q2.x;
    unsigned long long k3 = ((unsigned long long)q3.y << 32) | q3.x;
    if (k1 > k0) { k0 = k1; q0 = q1; z0 = z1; }
    if (k3 > k2) { k2 = k3; q2 = q3; z2 = z3; }
    if (k2 > k0) { k0 = k2; q0 = q2; z0 = z2; }
    cx = __uint_as_float(q0.z);
    cy = __uint_as_float(q0.w);
    cz = __uint_as_float(z0);
  }
}

// ---------------------------------------------------------------------------
// Ball query (unchanged, bit-exact).
// ---------------------------------------------------------------------------
__global__ __launch_bounds__(256) void ball_kernel(const float* __restrict__ xyz,
                                                   const float* __restrict__ newxyz,
                                                   int* __restrict__ idx) {
  const int b = blockIdx.x;
  const int s = blockIdx.y * 4 + (threadIdx.x >> 6);
  const int lane = threadIdx.x & 63;
  const float* X = xyz + (size_t)b * 3 * NN;
  const float cx = newxyz[b * 3 * NP + s];
  const float cy = newxyz[b * 3 * NP + NP + s];
  const float cz = newxyz[b * 3 * NP + 2 * NP + s];
  int* row = idx + ((size_t)(b * NP + s)) * NS;
  const float r2 = (float)(0.2 * 0.2);
  int total = 0, first = 0;
  bool havefirst = false;
  for (int c0 = 0; c0 < NN; c0 += 64) {
    int n = c0 + lane;
    float d2 = sqdist(X[n] - cx, X[NN + n] - cy, X[2 * NN + n] - cz);
    bool hit = d2 < r2;
    unsigned long long mask = __ballot(hit);
    if (!havefirst && mask) {
      first = c0 + __builtin_ctzll(mask);
      havefirst = true;
    }
    if (hit) {
      int pos = total + (int)__popcll(mask & ((1ull << lane) - 1ull));
      if (pos < NS) row[pos] = n;
    }
    total += (int)__popcll(mask);
    if (total >= NS) break;
  }
  if (total < NS && lane >= total && lane < NS) row[lane] = first;
}

// ---------------------------------------------------------------------------
// MFMA MLP: 128 cols/block (4 s), f16 activations in LDS [col][k], waves
// split output rows (each streams only its weight slice; owns full o-rows
// so maxpool is an in-wave shuffle). a2 aliases h. fp32 accumulate.
// ---------------------------------------------------------------------------
#define HSTR 104   // hT stride in f16 (96 padded)
#define A1STR 72   // a1 stride (64 padded)
#define A2STR 136  // a2 stride (128 padded)
#define A1OFF 17408

__global__ __launch_bounds__(256) void mlp_kernel(
    const float* __restrict__ xyzT, const _Float16* __restrict__ featF,
    const int* __restrict__ idx, const float* __restrict__ newxyz,
    const _Float16* __restrict__ W1f, const float* __restrict__ b1,
    const _Float16* __restrict__ W2f, const float* __restrict__ b2,
    const _Float16* __restrict__ W3f, const float* __restrict__ b3, float* __restrict__ out) {
  __shared__ _Float16 smem[17408 + 9216];  // 52 KB: h/a2 alias region + a1
  _Float16* hT = smem;
  _Float16* a1T = smem + A1OFF;
  const int b = blockIdx.x;
  const int s0 = blockIdx.y * 4;
  const int t = threadIdx.x;
  const int lane = t & 63, w = t >> 6;

  // ---- gather: hT[128 cols][96 k] (k: 0..63 feat, 64..66 relxyz, 67..95 zero)
  {
    const int col = t & 127, hf = t >> 7;
    const int s = s0 + (col >> 5), k = col & 31;
    const int n = idx[((size_t)(b * NP + s)) * NS + k];
    const _Float16* F = featF + (size_t)(b * NN + n) * NC;
#pragma unroll
    for (int j = 0; j < 4; ++j) {
      int p = hf * 4 + j;
      *(f16x8*)(&hT[col * HSTR + p * 8]) = *(const f16x8*)(F + p * 8);
    }
    if (hf == 0) {
      float4 pnt = ((const float4*)xyzT)[(size_t)b * NN + n];
      float cx = newxyz[b * 3 * NP + s];
      float cy = newxyz[b * 3 * NP + NP + s];
      float cz = newxyz[b * 3 * NP + 2 * NP + s];
      f16x8 v = {};
      v[0] = (_Float16)(pnt.x - cx);
      v[1] = (_Float16)(pnt.y - cy);
      v[2] = (_Float16)(pnt.z - cz);
      *(f16x8*)(&hT[col * HSTR + 64]) = v;
    } else {
      f16x8 z = {};
      *(f16x8*)(&hT[col * HSTR + 72]) = z;
      *(f16x8*)(&hT[col * HSTR + 80]) = z;
      *(f16x8*)(&hT[col * HSTR + 88]) = z;
    }
  }
  __syncthreads();

  const int cl = lane & 15;  // A row / B col within tile
  const int kg = lane >> 4;  // k-group; D row group

  // ---- layer 1: K=96, O=64; wave w owns rows w*16..+15
  {
    f32x4 acc[8];
    {
      f32x4 bb = *(const f32x4*)(b1 + w * 16 + kg * 4);
#pragma unroll
      for (int ct = 0; ct < 8; ++ct) acc[ct] = bb;
    }
#pragma unroll
    for (int ks = 0; ks < 3; ++ks) {
      f16x8 A = *(const f16x8*)(W1f + (w * 16 + cl) * 96 + ks * 32 + kg * 8);
#pragma unroll
      for (int ct = 0; ct < 8; ++ct) {
        f16x8 B = *(const f16x8*)(&hT[(ct * 16 + cl) * HSTR + ks * 32 + kg * 8]);
        acc[ct] = __builtin_amdgcn_mfma_f32_16x16x32_f16(A, B, acc[ct], 0, 0, 0);
      }
    }
#pragma unroll
    for (int ct = 0; ct < 8; ++ct) {
      f16x4 v;
#pragma unroll
      for (int i2 = 0; i2 < 4; ++i2) v[i2] = (_Float16)fmaxf(acc[ct][i2], 0.f);
      *(f16x4*)(&a1T[(ct * 16 + cl) * A1STR + w * 16 + kg * 4]) = v;
    }
  }
  __syncthreads();

  // ---- layer 2: K=64, O=128; wave w owns rows w*32..+31 (a2 aliases h)
  {
    f32x4 acc[2][8];
#pragma unroll
    for (int r = 0; r < 2; ++r) {
      f32x4 bb = *(const f32x4*)(b2 + w * 32 + r * 16 + kg * 4);
#pragma unroll
      for (int ct = 0; ct < 8; ++ct) acc[r][ct] = bb;
    }
#pragma unroll
    for (int ks = 0; ks < 2; ++ks) {
      f16x8 A0 = *(const f16x8*)(W2f + (w * 32 + cl) * 64 + ks * 32 + kg * 8);
      f16x8 A1 = *(const f16x8*)(W2f + (w * 32 + 16 + cl) * 64 + ks * 32 + kg * 8);
#pragma unroll
      for (int ct = 0; ct < 8; ++ct) {
        f16x8 B = *(const f16x8*)(&a1T[(ct * 16 + cl) * A1STR + ks * 32 + kg * 8]);
        acc[0][ct] = __builtin_amdgcn_mfma_f32_16x16x32_f16(A0, B, acc[0][ct], 0, 0, 0);
        acc[1][ct] = __builtin_amdgcn_mfma_f32_16x16x32_f16(A1, B, acc[1][ct], 0, 0, 0);
      }
    }
#pragma unroll
    for (int r = 0; r < 2; ++r)
#pragma unroll
      for (int ct = 0; ct < 8; ++ct) {
        f16x4 v;
#pragma unroll
        for (int i2 = 0; i2 < 4; ++i2) v[i2] = (_Float16)fmaxf(acc[r][ct][i2], 0.f);
        *(f16x4*)(&hT[(ct * 16 + cl) * A2STR + w * 32 + r * 16 + kg * 4]) = v;
      }
  }
  __syncthreads();

  // ---- layer 3: K=128, O=256; wave w owns rows w*64..+63; fused maxpool
  float* out2 = out + NB * 3 * NP;
#pragma unroll
  for (int rh = 0; rh < 2; ++rh) {
    f32x4 acc[2][8];
#pragma unroll
    for (int r = 0; r < 2; ++r) {
      f32x4 bb = *(const f32x4*)(b3 + w * 64 + rh * 32 + r * 16 + kg * 4);
#pragma unroll
      for (int ct = 0; ct < 8; ++ct) acc[r][ct] = bb;
    }
#pragma unroll
    for (int ks = 0; ks < 4; ++ks) {
      f16x8 A0 = *(const f16x8*)(W3f + (w * 64 + rh * 32 + cl) * 128 + ks * 32 + kg * 8);
      f16x8 A1 = *(const f16x8*)(W3f + (w * 64 + rh * 32 + 16 + cl) * 128 + ks * 32 + kg * 8);
#pragma unroll
      for (int ct = 0; ct < 8; ++ct) {
        f16x8 B = *(const f16x8*)(&hT[(ct * 16 + cl) * A2STR + ks * 32 + kg * 8]);
        acc[0][ct] = __builtin_amdgcn_mfma_f32_16x16x32_f16(A0, B, acc[0][ct], 0, 0, 0);
        acc[1][ct] = __builtin_amdgcn_mfma_f32_16x16x32_f16(A1, B, acc[1][ct], 0, 0, 0);
      }
    }
#pragma unroll
    for (int r = 0; r < 2; ++r)
#pragma unroll
      for (int sl = 0; sl < 4; ++sl) {
        float vv[4];
#pragma unroll
        for (int i2 = 0; i2 < 4; ++i2) {
          float m0 = fmaxf(acc[r][sl * 2][i2], 0.f);
          float m1 = fmaxf(acc[r][sl * 2 + 1][i2], 0.f);
          float mv = fmaxf(m0, m1);
          mv = fmaxf(mv, __shfl_xor(mv, 1, 64));
          mv = fmaxf(mv, __shfl_xor(mv, 2, 64));
          mv = fmaxf(mv, __shfl_xor(mv, 4, 64));
          mv = fmaxf(mv, __shfl_xor(mv, 8, 64));
          vv[i2] = mv;
        }
        if (cl == 0) {
          int ob = w * 64 + rh * 32 + r * 16 + kg * 4;
#pragma unroll
          for (int i2 = 0; i2 < 4; ++i2)
            out2[((size_t)(b * 256 + ob + i2)) * NP + s0 + sl] = vv[i2];
        }
      }
  }
}

extern "C" void kernel_launch(void* const* d_in, const int* in_sizes, int n_in, void* d_out,
                              int out_size, void* d_ws, size_t ws_size, hipStream_t stream) {
  const float* xyz = (const float*)d_in[0];
  const float* feat = (const float*)d_in[1];
  const float* W1 = (const float*)d_in[2];
  const float* b1 = (const float*)d_in[3];
  const float* W2 = (const float*)d_in[4];
  const float* b2 = (const float*)d_in[5];
  const float* W3 = (const float*)d_in[6];
  const float* b3 = (const float*)d_in[7];
  float* out = (float*)d_out;
  char* ws = (char*)d_ws;
  float* xyzT = (float*)ws;                               // 512 KB
  _Float16* featF = (_Float16*)(ws + 524288);             // 4 MB
  int* idx = (int*)(ws + 4718592);                        // 1 MB
  _Float16* W1f = (_Float16*)(ws + 5767168);              // 12 KB
  _Float16* W2f = (_Float16*)(ws + 5779456);              // 16 KB
  _Float16* W3f = (_Float16*)(ws + 5795840);              // 64 KB

  hipLaunchKernelGGL(prep_kernel, dim3(NB, 32), dim3(256), 0, stream, feat, xyz, featF, xyzT);
  hipLaunchKernelGGL(wconv_kernel, dim3(128), dim3(256), 0, stream, W1, W2, W3, W1f, W2f, W3f);
  hipLaunchKernelGGL(fps_kernel, dim3(NB), dim3(256), 0, stream, xyz, out);
  hipLaunchKernelGGL(ball_kernel, dim3(NB, 128), dim3(256), 0, stream, xyz, out, idx);
  hipLaunchKernelGGL(mlp_kernel, dim3(NB, 128), dim3(256), 0, stream, xyzT, featF, idx, out, W1f,
                     b1, W2f, b2, W3f, b3, out);
}